// Round 1
// baseline (273.971 us; speedup 1.0000x reference)
//
#include <hip/hip_runtime.h>

// Problem constants
#define BATCH 8
#define NN 32768
#define KK 128
#define NCHUNK 32                 // N-chunks (partial grams)
#define CHUNK (NN / NCHUNK)       // 1024 rows per block
#define TILE 32                   // n-rows staged in LDS per step
#define NTILES (CHUNK / TILE)     // 32
#define NITER 20                  // CG iterations (kappa ~1.3 -> overkill, safe)

// Workspace layout (float offsets).  Total = 17,436,672 bytes.
#define GP_OFF ((size_t)0)                                  // [B][NCHUNK][128][128] partial grams
#define MP_OFF ((size_t)BATCH * NCHUNK * KK * KK)           // [B][NCHUNK][128]     partial m
#define G_OFF  (MP_OFF + (size_t)BATCH * NCHUNK * KK)       // [B][128][128]        final G
#define MV_OFF (G_OFF + (size_t)BATCH * KK * KK)            // [B][128]             final m

// ---------------------------------------------------------------------------
// K1: partial Gram + partial m.  One block = (batch, n-chunk).
// Thread tile: 8 rows x 8 cols of the 128x128 gram. 256 threads = 16x16 tiles.
// mult tile (32 x 128 f32) double-buffered in LDS, register-prefetched.
// ---------------------------------------------------------------------------
__global__ __launch_bounds__(256, 1) void gram_partial_kernel(
    const float* __restrict__ data, const float* __restrict__ mask,
    const float* __restrict__ mult, float* __restrict__ ws)
{
    const int tid   = threadIdx.x;
    const int b     = blockIdx.x / NCHUNK;
    const int chunk = blockIdx.x % NCHUNK;
    const int n0    = chunk * CHUNK;

    __shared__ float tile[2][TILE][KK];   // 2 x 16 KB
    __shared__ float w2s[2][TILE];
    __shared__ float mds[2][TILE];

    const int g = tid >> 4;   // krow group 0..15 -> rows 8g..8g+7
    const int c = tid & 15;   // kcol group 0..15 -> cols 8c..8c+7

    float acc[8][8];
#pragma unroll
    for (int i = 0; i < 8; ++i)
#pragma unroll
        for (int j = 0; j < 8; ++j) acc[i][j] = 0.f;
    float mAcc = 0.f;

    const float4* mult4 = reinterpret_cast<const float4*>(mult);

    // Prologue: prefetch tile 0 into registers
    float4 reg[4];
    float mv = 0.f, dv = 0.f;
    {
        const int base4 = n0 * (KK / 4);
#pragma unroll
        for (int u = 0; u < 4; ++u) reg[u] = mult4[base4 + u * 256 + tid];
        if (tid < TILE) {
            mv = mask[b * NN + n0 + tid];
            dv = data[b * NN + n0 + tid];
        }
    }

    int cur = 0;
    for (int t = 0; t < NTILES; ++t) {
        // write staged registers into LDS buffer `cur`
        float4* t4 = reinterpret_cast<float4*>(&tile[cur][0][0]);
#pragma unroll
        for (int u = 0; u < 4; ++u) t4[u * 256 + tid] = reg[u];
        if (tid < TILE) {
            w2s[cur][tid] = mv * mv;
            mds[cur][tid] = mv * dv;
        }
        // issue global loads for tile t+1 (latency hidden under compute)
        if (t + 1 < NTILES) {
            const int nn    = n0 + (t + 1) * TILE;
            const int base4 = nn * (KK / 4);
#pragma unroll
            for (int u = 0; u < 4; ++u) reg[u] = mult4[base4 + u * 256 + tid];
            if (tid < TILE) {
                mv = mask[b * NN + nn + tid];
                dv = data[b * NN + nn + tid];
            }
        }
        __syncthreads();   // LDS writes visible; prev compute done before next write

        const float* rowbase = &tile[cur][0][0];
        const float* w2p = w2s[cur];
        const float* mdp = mds[cur];
#pragma unroll 8
        for (int r = 0; r < TILE; ++r) {
            const float  w2  = w2p[r];
            const float* row = rowbase + r * KK;
            float4 a0 = *reinterpret_cast<const float4*>(row + g * 8);
            float4 a1 = *reinterpret_cast<const float4*>(row + g * 8 + 4);
            float4 b0 = *reinterpret_cast<const float4*>(row + c * 8);
            float4 b1 = *reinterpret_cast<const float4*>(row + c * 8 + 4);
            float a[8] = { a0.x * w2, a0.y * w2, a0.z * w2, a0.w * w2,
                           a1.x * w2, a1.y * w2, a1.z * w2, a1.w * w2 };
            float bb[8] = { b0.x, b0.y, b0.z, b0.w, b1.x, b1.y, b1.z, b1.w };
#pragma unroll
            for (int i = 0; i < 8; ++i)
#pragma unroll
                for (int j = 0; j < 8; ++j)
                    acc[i][j] = fmaf(a[i], bb[j], acc[i][j]);
            // partial m: threads 0..127 own k = tid (waves 0-1, uniform branch)
            if (tid < KK) mAcc = fmaf(mdp[r], row[tid], mAcc);
        }
        cur ^= 1;
    }

    // Epilogue: write partial gram (disjoint, no atomics)
    float* Gp = ws + GP_OFF + (size_t)(b * NCHUNK + chunk) * (KK * KK);
#pragma unroll
    for (int i = 0; i < 8; ++i) {
        float4 v0 = make_float4(acc[i][0], acc[i][1], acc[i][2], acc[i][3]);
        float4 v1 = make_float4(acc[i][4], acc[i][5], acc[i][6], acc[i][7]);
        float4* dst = reinterpret_cast<float4*>(Gp + (g * 8 + i) * KK + c * 8);
        dst[0] = v0;
        dst[1] = v1;
    }
    if (tid < KK) ws[MP_OFF + (size_t)(b * NCHUNK + chunk) * KK + tid] = mAcc;
}

// ---------------------------------------------------------------------------
// K2: reduce partials over chunks, add sigma^2 on the diagonal.
// grid = BATCH*64 blocks x 256 threads; each thread one gram entry.
// ---------------------------------------------------------------------------
__global__ __launch_bounds__(256, 1) void reduce_kernel(
    const float* __restrict__ sig, float* __restrict__ ws)
{
    const int tid = threadIdx.x;
    const int b   = blockIdx.x >> 6;
    const int jb  = blockIdx.x & 63;
    const int j   = jb * 256 + tid;

    const float* Gp = ws + GP_OFF + (size_t)b * NCHUNK * KK * KK;
    float s = 0.f;
#pragma unroll
    for (int cc = 0; cc < NCHUNK; ++cc) s += Gp[(size_t)cc * KK * KK + j];
    const int row = j >> 7, col = j & 127;
    if (row == col) s += sig[0];
    ws[G_OFF + (size_t)b * KK * KK + j] = s;

    if (jb == 0 && tid < KK) {
        const float* Mp = ws + MP_OFF + (size_t)b * NCHUNK * KK;
        float ms = 0.f;
#pragma unroll
        for (int cc = 0; cc < NCHUNK; ++cc) ms += Mp[cc * KK + tid];
        ws[MV_OFF + (size_t)b * KK + tid] = ms;
    }
}

// ---------------------------------------------------------------------------
// K3: per-batch CG solve of G x = m.  8 blocks x 128 threads (thread = row).
// G row i loaded to registers via COLUMN i (G symmetric -> coalesced reads).
// ---------------------------------------------------------------------------
__device__ __forceinline__ float blockDot(float a, float bvl, float* red)
{
    float v = a * bvl;
#pragma unroll
    for (int off = 32; off > 0; off >>= 1) v += __shfl_down(v, off, 64);
    const int wid = threadIdx.x >> 6;
    if ((threadIdx.x & 63) == 0) red[wid] = v;
    __syncthreads();
    float s = red[0] + red[1];
    __syncthreads();
    return s;
}

__global__ __launch_bounds__(128, 1) void solve_kernel(
    const float* __restrict__ ws, float* __restrict__ out)
{
    const int b = blockIdx.x;
    const int i = threadIdx.x;   // row 0..127

    __shared__ float ps[KK];
    __shared__ float red[2];

    const float* G = ws + G_OFF + (size_t)b * KK * KK;

    // Row i of symmetric G == column i: G[j*KK + i] -> coalesced across threads
    float Gr[KK];
#pragma unroll
    for (int j = 0; j < KK; ++j) Gr[j] = G[j * KK + i];

    float mvv = ws[MV_OFF + (size_t)b * KK + i];
    float x = 0.f, r = mvv, p = r;
    ps[i] = p;
    float rs = blockDot(r, r, red);   // internal barriers also publish ps

    for (int it = 0; it < NITER; ++it) {
        float q0 = 0.f, q1 = 0.f, q2 = 0.f, q3 = 0.f;
#pragma unroll
        for (int u = 0; u < 32; ++u) {
            float4 pv = *reinterpret_cast<const float4*>(&ps[4 * u]);
            q0 = fmaf(Gr[4 * u + 0], pv.x, q0);
            q1 = fmaf(Gr[4 * u + 1], pv.y, q1);
            q2 = fmaf(Gr[4 * u + 2], pv.z, q2);
            q3 = fmaf(Gr[4 * u + 3], pv.w, q3);
        }
        float q = (q0 + q1) + (q2 + q3);

        float pq    = blockDot(p, q, red);
        float alpha = rs / (pq + 1e-30f);
        x = fmaf(alpha, p, x);
        r = fmaf(-alpha, q, r);
        float rs2  = blockDot(r, r, red);
        float beta = rs2 / (rs + 1e-30f);
        rs = rs2;
        p  = fmaf(beta, p, r);
        ps[i] = p;
        __syncthreads();
    }
    out[(size_t)b * KK + i] = x;
}

// ---------------------------------------------------------------------------
extern "C" void kernel_launch(void* const* d_in, const int* in_sizes, int n_in,
                              void* d_out, int out_size, void* d_ws, size_t ws_size,
                              hipStream_t stream)
{
    const float* data = (const float*)d_in[0];
    const float* mask = (const float*)d_in[1];
    const float* mult = (const float*)d_in[2];
    const float* sig  = (const float*)d_in[3];
    float* ws  = (float*)d_ws;
    float* out = (float*)d_out;

    gram_partial_kernel<<<BATCH * NCHUNK, 256, 0, stream>>>(data, mask, mult, ws);
    reduce_kernel<<<BATCH * 64, 256, 0, stream>>>(sig, ws);
    solve_kernel<<<BATCH, 128, 0, stream>>>(ws, out);
}

// Round 3
// 117.679 us; speedup vs baseline: 2.3281x; 2.3281x over previous
//
#include <hip/hip_runtime.h>

#define BATCH 8
#define NN 32768
#define KK 128
#define NCHUNK 32
#define CHUNK 1024            // NN / NCHUNK
#define NST 16                // super-tiles of 64 n per chunk
#define NITER 12              // CG iterations (kappa ~1.28)

typedef __attribute__((ext_vector_type(8)))  _Float16 half8;
typedef __attribute__((ext_vector_type(4)))  _Float16 half4;
typedef __attribute__((ext_vector_type(16))) float    f32x16;

// ---- workspace byte offsets (total ~15.2 MB, under proven-safe 17.4 MB) ----
#define MT_OFF   0ull                      // multT fp16 [128][32768]
#define WH_OFF   (MT_OFF + 8388608ull)     // wh fp16 [8][32768]  (mask)
#define DH_OFF   (WH_OFF + 524288ull)      // dh fp16 [8][32768]  (data)
#define GP_OFF   (DH_OFF + 524288ull)      // Gp fp16 [8][32][10][1024] partial tiles
#define MP_OFF   (GP_OFF + 5242880ull)     // Mp f32  [8][32][128]
#define G_OFF    (MP_OFF + 131072ull)      // G  f32  [8][128][128]

// ---------------------------------------------------------------------------
// K0a: convert mask/data to fp16 (vectorized f32x4 -> f16x4)
// ---------------------------------------------------------------------------
__global__ __launch_bounds__(256) void conv_kernel(
    const float* __restrict__ data, const float* __restrict__ mask,
    unsigned char* __restrict__ ws)
{
    const int gid = blockIdx.x * 256 + threadIdx.x;   // 65536 threads x 4 elems
    const float4 d4 = ((const float4*)data)[gid];
    const float4 m4 = ((const float4*)mask)[gid];
    half4 w = { (_Float16)m4.x, (_Float16)m4.y, (_Float16)m4.z, (_Float16)m4.w };
    half4 d = { (_Float16)d4.x, (_Float16)d4.y, (_Float16)d4.z, (_Float16)d4.w };
    ((half4*)(ws + WH_OFF))[gid] = w;
    ((half4*)(ws + DH_OFF))[gid] = d;
}

// ---------------------------------------------------------------------------
// K0b: transpose mult [32768][128] f32 -> multT [128][32768] fp16
// ---------------------------------------------------------------------------
__global__ __launch_bounds__(256) void transpose_kernel(
    const float* __restrict__ mult, unsigned char* __restrict__ ws)
{
    __shared__ _Float16 t[128][136];          // +8 fp16 pad vs 128
    const int tid = threadIdx.x;
    const int n0  = blockIdx.x * 128;
    const float4* m4 = (const float4*)mult;
#pragma unroll
    for (int u = 0; u < 16; ++u) {            // 16 x 256 = 4096 float4 = full 128x128 tile
        const int c16 = u * 256 + tid;        // 16B chunk id in 128x128 tile
        const int n  = c16 >> 5;              // 32 float4 per row
        const int kq = c16 & 31;
        float4 v = m4[(size_t)(n0 + n) * 32 + kq];
        half4 h = { (_Float16)v.x, (_Float16)v.y, (_Float16)v.z, (_Float16)v.w };
        *(half4*)&t[n][kq * 4] = h;
    }
    __syncthreads();
    _Float16* mt = (_Float16*)(ws + MT_OFF);
    const int k = tid & 127, nh = tid >> 7;
#pragma unroll
    for (int i = 0; i < 8; ++i) {
        const int nb = nh * 64 + i * 8;
        half8 v;
#pragma unroll
        for (int j = 0; j < 8; ++j) v[j] = t[nb + j][k];
        *(half8*)(mt + (size_t)k * NN + n0 + nb) = v;
    }
}

// ---------------------------------------------------------------------------
// K1: MFMA gram partials (upper-tri 10 tiles of 32x32) + m partials.
// Block = (batch, 1024-n chunk), 4 waves; wave w owns n-slice w*16 within each
// 64-n super-tile and accumulates a FULL upper-tri gram; cross-wave reduce at
// the end in LDS.  LDS tile [128 k][64 n] fp16, XOR granule swizzle
// slot = g ^ (k&7) -> conflict-free ds_write_b128 and ds_read_b128.
// Same fragment fed to MFMA A and B slots: any per-lane k-permutation cancels
// (pi_A == pi_B), so the contraction over n is layout-exact.
// ---------------------------------------------------------------------------
__global__ __launch_bounds__(256, 1) void gram_kernel(
    unsigned char* __restrict__ ws)
{
    __shared__ unsigned char smem[36864];     // 2x16KB tiles | 2KB w | 2KB d
    const int tid = threadIdx.x;
    const int b     = blockIdx.x >> 5;
    const int chunk = blockIdx.x & 31;
    const int n0    = chunk * CHUNK;
    const int w = tid >> 6, l = tid & 63;

    const _Float16* mt = (const _Float16*)(ws + MT_OFF);

    // stage w-chunk / d-chunk (fp16, 2KB each)
    if (tid < 128) {
        half8 wv = *(const half8*)((const _Float16*)(ws + WH_OFF) + (size_t)b * NN + n0 + tid * 8);
        half8 dv = *(const half8*)((const _Float16*)(ws + DH_OFF) + (size_t)b * NN + n0 + tid * 8);
        *(half8*)(smem + 32768 + tid * 16) = wv;
        *(half8*)(smem + 34816 + tid * 16) = dv;
    }

    // staging addressing: thread -> (k-row, data-granule)
    const int krow = tid >> 3;                  // 0..31 (+q*32)
    const int gd   = tid & 7;
    const _Float16* gsrc0 = mt + (size_t)krow * NN + n0 + gd * 8;
    const int wslot = (gd ^ (krow & 7)) * 16;   // swizzled byte slot in 128B row

    uint4 S0, S1, S2, S3;
#define GLOAD(st_) { const _Float16* p = gsrc0 + (size_t)(st_) * 64;          \
        S0 = *(const uint4*)(p);                                              \
        S1 = *(const uint4*)(p + (size_t)32 * NN);                            \
        S2 = *(const uint4*)(p + (size_t)64 * NN);                            \
        S3 = *(const uint4*)(p + (size_t)96 * NN); }
#define DSWRITE(buf_) { unsigned char* bp = smem + (buf_) * 16384 + krow * 128 + wslot; \
        *(uint4*)(bp)         = S0;  *(uint4*)(bp + 4096)  = S1;              \
        *(uint4*)(bp + 8192)  = S2;  *(uint4*)(bp + 12288) = S3; }

    // frag read addressing: wave w, tile t, lane l
    const int frow  = (l & 31) * 128;
    const int fslot = ((w * 2 + (l >> 5)) ^ (l & 7)) * 16;
    const int wdoff = w * 32 + (l >> 5) * 16;   // byte off into w/d chunk (+st*128)

    f32x16 a00 = {}, a01 = {}, a02 = {}, a03 = {}, a11 = {},
           a12 = {}, a13 = {}, a22 = {}, a23 = {}, a33 = {};
    float macc0 = 0.f, macc1 = 0.f, macc2 = 0.f, macc3 = 0.f;

    GLOAD(0);
    __syncthreads();            // w/d chunk staged
    DSWRITE(0);
    GLOAD(1);
    __syncthreads();            // buf0 ready

#pragma unroll 2
    for (int st = 0; st < NST; ++st) {
        const int cur = st & 1;
        if (st < NST - 1) {
            DSWRITE(cur ^ 1);
            if (st < NST - 2) GLOAD(st + 2);
        }
        const unsigned char* tb = smem + cur * 16384;
        const half8 wf = *(const half8*)(smem + 32768 + st * 128 + wdoff);
        const half8 df = *(const half8*)(smem + 34816 + st * 128 + wdoff);
        half8 f0 = *(const half8*)(tb +     0 + frow + fslot) * wf;
        half8 f1 = *(const half8*)(tb +  4096 + frow + fslot) * wf;
        half8 f2 = *(const half8*)(tb +  8192 + frow + fslot) * wf;
        half8 f3 = *(const half8*)(tb + 12288 + frow + fslot) * wf;
        // m partial: lane holds k = q*32 + (l&31)
#pragma unroll
        for (int j = 0; j < 8; ++j) {
            const float dj = (float)df[j];
            macc0 = fmaf((float)f0[j], dj, macc0);
            macc1 = fmaf((float)f1[j], dj, macc1);
            macc2 = fmaf((float)f2[j], dj, macc2);
            macc3 = fmaf((float)f3[j], dj, macc3);
        }
        a00 = __builtin_amdgcn_mfma_f32_32x32x16_f16(f0, f0, a00, 0, 0, 0);
        a01 = __builtin_amdgcn_mfma_f32_32x32x16_f16(f0, f1, a01, 0, 0, 0);
        a02 = __builtin_amdgcn_mfma_f32_32x32x16_f16(f0, f2, a02, 0, 0, 0);
        a03 = __builtin_amdgcn_mfma_f32_32x32x16_f16(f0, f3, a03, 0, 0, 0);
        a11 = __builtin_amdgcn_mfma_f32_32x32x16_f16(f1, f1, a11, 0, 0, 0);
        a12 = __builtin_amdgcn_mfma_f32_32x32x16_f16(f1, f2, a12, 0, 0, 0);
        a13 = __builtin_amdgcn_mfma_f32_32x32x16_f16(f1, f3, a13, 0, 0, 0);
        a22 = __builtin_amdgcn_mfma_f32_32x32x16_f16(f2, f2, a22, 0, 0, 0);
        a23 = __builtin_amdgcn_mfma_f32_32x32x16_f16(f2, f3, a23, 0, 0, 0);
        a33 = __builtin_amdgcn_mfma_f32_32x32x16_f16(f3, f3, a33, 0, 0, 0);
        __syncthreads();
    }

    // ---- epilogue: m partials ----
    {
        float* M = (float*)(smem + 32768);   // 4KB, w/d chunks dead now
        const int base = (w * 2 + (l >> 5)) * 128 + (l & 31);
        M[base +  0] = macc0;  M[base + 32] = macc1;
        M[base + 64] = macc2;  M[base + 96] = macc3;
    }
    // ---- epilogue: gram tiles, 5 phases of 2 tiles, cross-wave sum in LDS ----
    _Float16* Gp = (_Float16*)(ws + GP_OFF) + (size_t)(b * NCHUNK + chunk) * 10240;
    float* Mp = (float*)(ws + MP_OFF) + (size_t)(b * NCHUNK + chunk) * KK;
    float* R = (float*)smem;

#define PHASE(p_, A0_, A1_)                                                    \
    {                                                                          \
        *(f32x16*)(R + (w * 2 + 0) * 1024 + l * 16) = A0_;                     \
        *(f32x16*)(R + (w * 2 + 1) * 1024 + l * 16) = A1_;                     \
        __syncthreads();                                                       \
        _Pragma("unroll")                                                      \
        for (int pass = 0; pass < 2; ++pass) {                                 \
            const int e = pass * 1024 + tid * 4;                               \
            float4 s0 = *(float4*)(R + e);                                     \
            float4 s1 = *(float4*)(R + 2048 + e);                              \
            float4 s2 = *(float4*)(R + 4096 + e);                              \
            float4 s3 = *(float4*)(R + 6144 + e);                              \
            float sx = s0.x + s1.x + s2.x + s3.x;                              \
            float sy = s0.y + s1.y + s2.y + s3.y;                              \
            float sz = s0.z + s1.z + s2.z + s3.z;                              \
            float sw = s0.w + s1.w + s2.w + s3.w;                              \
            half4 h = { (_Float16)sx, (_Float16)sy, (_Float16)sz, (_Float16)sw }; \
            *(half4*)(Gp + (p_) * 2048 + e) = h;                               \
        }                                                                      \
        if ((p_) == 0 && tid < 128) {                                          \
            const float* M = (const float*)(smem + 32768);                     \
            float s = 0.f;                                                     \
            _Pragma("unroll")                                                  \
            for (int c8 = 0; c8 < 8; ++c8) s += M[c8 * 128 + tid];             \
            Mp[tid] = s;                                                       \
        }                                                                      \
        __syncthreads();                                                       \
    }

    PHASE(0, a00, a01)
    PHASE(1, a02, a03)
    PHASE(2, a11, a12)
    PHASE(3, a13, a22)
    PHASE(4, a23, a33)
#undef PHASE
#undef GLOAD
#undef DSWRITE
}

// ---------------------------------------------------------------------------
// K2: reduce fp16 partial tiles -> G f32 (full matrix, mirrored) + sigma^2 I.
// Decodes MFMA C/D layout: col = lane&31, row = (reg&3)+8*(reg>>2)+4*(lane>>5).
// ---------------------------------------------------------------------------
__global__ __launch_bounds__(256) void reduce_kernel(
    const float* __restrict__ sig, unsigned char* __restrict__ ws)
{
    const int tid = threadIdx.x;
    const int b  = blockIdx.x >> 6;
    const int jb = blockIdx.x & 63;
    const int j  = jb * 256 + tid;          // 0..16383
    const int r = j >> 7, c = j & 127;
    const int t = r >> 5, u = c >> 5;
    int tt, uu, rr, cc;
    if (t <= u) { tt = t; uu = u; rr = r & 31; cc = c & 31; }
    else        { tt = u; uu = t; rr = c & 31; cc = r & 31; }
    const int tidx = tt * 4 - tt * (tt + 1) / 2 + uu;   // upper-tri flat index
    const int lane = cc + 32 * ((rr >> 2) & 1);
    const int reg  = (rr & 3) + 4 * ((rr >> 3) & 3);
    const _Float16* Gp = (const _Float16*)(ws + GP_OFF)
                       + (size_t)b * NCHUNK * 10240
                       + (size_t)tidx * 1024 + lane * 16 + reg;
    float s = 0.f;
#pragma unroll
    for (int ch = 0; ch < NCHUNK; ++ch) s += (float)Gp[(size_t)ch * 10240];
    if (r == c) s += sig[0];
    ((float*)(ws + G_OFF))[(size_t)b * 16384 + j] = s;
}

// ---------------------------------------------------------------------------
// K3: per-batch m reduce + CG solve of G x = m.  8 blocks x 128 threads.
// ---------------------------------------------------------------------------
__device__ __forceinline__ float blockDot(float a, float bvl, float* red)
{
    float v = a * bvl;
#pragma unroll
    for (int off = 32; off > 0; off >>= 1) v += __shfl_down(v, off, 64);
    const int wid = threadIdx.x >> 6;
    if ((threadIdx.x & 63) == 0) red[wid] = v;
    __syncthreads();
    float s = red[0] + red[1];
    __syncthreads();
    return s;
}

__global__ __launch_bounds__(128, 1) void solve_kernel(
    const unsigned char* __restrict__ ws, float* __restrict__ out)
{
    const int b = blockIdx.x;
    const int i = threadIdx.x;

    __shared__ float ps[KK];
    __shared__ float red[2];

    const float* G  = (const float*)(ws + G_OFF) + (size_t)b * 16384;
    const float* Mp = (const float*)(ws + MP_OFF) + (size_t)b * NCHUNK * KK;

    float Gr[KK];
#pragma unroll
    for (int j = 0; j < KK; ++j) Gr[j] = G[j * KK + i];   // symmetric: col i == row i

    float mvv = 0.f;
#pragma unroll
    for (int ch = 0; ch < NCHUNK; ++ch) mvv += Mp[ch * KK + i];

    float x = 0.f, r = mvv, p = r;
    ps[i] = p;
    float rs = blockDot(r, r, red);

    for (int it = 0; it < NITER; ++it) {
        float q0 = 0.f, q1 = 0.f, q2 = 0.f, q3 = 0.f;
#pragma unroll
        for (int u = 0; u < 32; ++u) {
            float4 pv = *reinterpret_cast<const float4*>(&ps[4 * u]);
            q0 = fmaf(Gr[4 * u + 0], pv.x, q0);
            q1 = fmaf(Gr[4 * u + 1], pv.y, q1);
            q2 = fmaf(Gr[4 * u + 2], pv.z, q2);
            q3 = fmaf(Gr[4 * u + 3], pv.w, q3);
        }
        float q = (q0 + q1) + (q2 + q3);

        float pq    = blockDot(p, q, red);
        float alpha = rs / (pq + 1e-30f);
        x = fmaf(alpha, p, x);
        r = fmaf(-alpha, q, r);
        float rs2  = blockDot(r, r, red);
        float beta = rs2 / (rs + 1e-30f);
        rs = rs2;
        p  = fmaf(beta, p, r);
        ps[i] = p;
        __syncthreads();
    }
    out[(size_t)b * KK + i] = x;
}

// ---------------------------------------------------------------------------
extern "C" void kernel_launch(void* const* d_in, const int* in_sizes, int n_in,
                              void* d_out, int out_size, void* d_ws, size_t ws_size,
                              hipStream_t stream)
{
    const float* data = (const float*)d_in[0];
    const float* mask = (const float*)d_in[1];
    const float* mult = (const float*)d_in[2];
    const float* sig  = (const float*)d_in[3];
    unsigned char* ws = (unsigned char*)d_ws;
    float* out = (float*)d_out;

    conv_kernel     <<<256, 256, 0, stream>>>(data, mask, ws);
    transpose_kernel<<<256, 256, 0, stream>>>(mult, ws);
    gram_kernel     <<<BATCH * NCHUNK, 256, 0, stream>>>(ws);
    reduce_kernel   <<<BATCH * 64, 256, 0, stream>>>(sig, ws);
    solve_kernel    <<<BATCH, 128, 0, stream>>>(ws, out);
}

// Round 4
// 103.142 us; speedup vs baseline: 2.6562x; 1.1409x over previous
//
#include <hip/hip_runtime.h>

#define BATCH 8
#define NN 32768
#define KK 128
#define NCHUNK 32
#define CHUNK 1024            // NN / NCHUNK
#define NST 16                // super-tiles of 64 n per chunk
#define NITER 8               // CG iterations (kappa ~1.4 -> ~11x/iter)

typedef __attribute__((ext_vector_type(8)))  _Float16 half8;
typedef __attribute__((ext_vector_type(4)))  _Float16 half4;
typedef __attribute__((ext_vector_type(16))) float    f32x16;

// ---- workspace byte offsets (total ~15.2 MB) ----
#define MT_OFF   0ull                      // multT fp16 [128][32768]
#define WH_OFF   (MT_OFF + 8388608ull)     // wh fp16 [8][32768]  (mask)
#define DH_OFF   (WH_OFF + 524288ull)      // dh fp16 [8][32768]  (data)
#define GP_OFF   (DH_OFF + 524288ull)      // Gp fp16 [8][32][10][1024] partial tiles
#define MP_OFF   (GP_OFF + 5242880ull)     // Mp f32  [8][32][128]
#define G_OFF    (MP_OFF + 131072ull)      // G  f32  [8][128][128]

// ---------------------------------------------------------------------------
// K0: fused conv (mask/data -> fp16) + transpose (mult f32 [N][K] -> multT
// fp16 [K][N]).  One block per 128-n tile.  Global writes COALESCED:
// 16 consecutive lanes write 16 consecutive half8 granules of one k-row.
// LDS staging tile XOR-swizzled (granule c4 = kq ^ ((n>>3)&7)) so the
// column-order read is ~conflict-free.
// ---------------------------------------------------------------------------
__global__ __launch_bounds__(256) void prep_kernel(
    const float* __restrict__ data, const float* __restrict__ mask,
    const float* __restrict__ mult, unsigned char* __restrict__ ws)
{
    __shared__ _Float16 t[128][136];
    const int tid = threadIdx.x;
    const int n0  = blockIdx.x * 128;

    // ---- conv part: this block's 128-n slice, all 8 batches ----
    {
        const int b = tid >> 5, q = tid & 31;
        const size_t src = (size_t)b * NN + n0 + q * 4;
        const float4 d4 = *(const float4*)(data + src);
        const float4 m4 = *(const float4*)(mask + src);
        half4 w = { (_Float16)m4.x, (_Float16)m4.y, (_Float16)m4.z, (_Float16)m4.w };
        half4 d = { (_Float16)d4.x, (_Float16)d4.y, (_Float16)d4.z, (_Float16)d4.w };
        *(half4*)((_Float16*)(ws + WH_OFF) + src) = w;
        *(half4*)((_Float16*)(ws + DH_OFF) + src) = d;
    }

    // ---- stage mult tile into LDS (swizzled), fp16 ----
    const float4* m4p = (const float4*)mult;
#pragma unroll
    for (int u = 0; u < 16; ++u) {            // 16 x 256 = 4096 float4 = full tile
        const int c16 = u * 256 + tid;
        const int n  = c16 >> 5;              // 0..127
        const int kq = c16 & 31;              // granule of 4 halfs
        float4 v = m4p[(size_t)(n0 + n) * 32 + kq];
        half4 h = { (_Float16)v.x, (_Float16)v.y, (_Float16)v.z, (_Float16)v.w };
        const int c4s = kq ^ ((n >> 3) & 7);  // XOR swizzle
        *(half4*)&t[n][c4s * 4] = h;
    }
    __syncthreads();

    // ---- coalesced transposed write ----
    _Float16* mt = (_Float16*)(ws + MT_OFF);
    const int g = tid & 15;                   // n-granule 0..15
#pragma unroll
    for (int i = 0; i < 8; ++i) {
        const int k = (tid >> 4) + i * 16;    // k-row
        const int c4 = (k >> 2) ^ 7;          // invariant part XORed below per row
        half8 v;
#pragma unroll
        for (int j = 0; j < 8; ++j) {
            const int n = g * 8 + j;
            const int cs = (k >> 2) ^ ((n >> 3) & 7);
            v[j] = t[n][cs * 4 + (k & 3)];
        }
        (void)c4;
        *(half8*)(mt + (size_t)k * NN + n0 + g * 8) = v;
    }
}

// ---------------------------------------------------------------------------
// K1: MFMA gram partials (upper-tri 10 tiles of 32x32) + m partials.
// (unchanged from validated R3 kernel)
// ---------------------------------------------------------------------------
__global__ __launch_bounds__(256, 1) void gram_kernel(
    unsigned char* __restrict__ ws)
{
    __shared__ unsigned char smem[36864];     // 2x16KB tiles | 2KB w | 2KB d
    const int tid = threadIdx.x;
    const int b     = blockIdx.x >> 5;
    const int chunk = blockIdx.x & 31;
    const int n0    = chunk * CHUNK;
    const int w = tid >> 6, l = tid & 63;

    const _Float16* mt = (const _Float16*)(ws + MT_OFF);

    if (tid < 128) {
        half8 wv = *(const half8*)((const _Float16*)(ws + WH_OFF) + (size_t)b * NN + n0 + tid * 8);
        half8 dv = *(const half8*)((const _Float16*)(ws + DH_OFF) + (size_t)b * NN + n0 + tid * 8);
        *(half8*)(smem + 32768 + tid * 16) = wv;
        *(half8*)(smem + 34816 + tid * 16) = dv;
    }

    const int krow = tid >> 3;
    const int gd   = tid & 7;
    const _Float16* gsrc0 = mt + (size_t)krow * NN + n0 + gd * 8;
    const int wslot = (gd ^ (krow & 7)) * 16;

    uint4 S0, S1, S2, S3;
#define GLOAD(st_) { const _Float16* p = gsrc0 + (size_t)(st_) * 64;          \
        S0 = *(const uint4*)(p);                                              \
        S1 = *(const uint4*)(p + (size_t)32 * NN);                            \
        S2 = *(const uint4*)(p + (size_t)64 * NN);                            \
        S3 = *(const uint4*)(p + (size_t)96 * NN); }
#define DSWRITE(buf_) { unsigned char* bp = smem + (buf_) * 16384 + krow * 128 + wslot; \
        *(uint4*)(bp)         = S0;  *(uint4*)(bp + 4096)  = S1;              \
        *(uint4*)(bp + 8192)  = S2;  *(uint4*)(bp + 12288) = S3; }

    const int frow  = (l & 31) * 128;
    const int fslot = ((w * 2 + (l >> 5)) ^ (l & 7)) * 16;
    const int wdoff = w * 32 + (l >> 5) * 16;

    f32x16 a00 = {}, a01 = {}, a02 = {}, a03 = {}, a11 = {},
           a12 = {}, a13 = {}, a22 = {}, a23 = {}, a33 = {};
    float macc0 = 0.f, macc1 = 0.f, macc2 = 0.f, macc3 = 0.f;

    GLOAD(0);
    __syncthreads();
    DSWRITE(0);
    GLOAD(1);
    __syncthreads();

#pragma unroll 2
    for (int st = 0; st < NST; ++st) {
        const int cur = st & 1;
        if (st < NST - 1) {
            DSWRITE(cur ^ 1);
            if (st < NST - 2) GLOAD(st + 2);
        }
        const unsigned char* tb = smem + cur * 16384;
        const half8 wf = *(const half8*)(smem + 32768 + st * 128 + wdoff);
        const half8 df = *(const half8*)(smem + 34816 + st * 128 + wdoff);
        half8 f0 = *(const half8*)(tb +     0 + frow + fslot) * wf;
        half8 f1 = *(const half8*)(tb +  4096 + frow + fslot) * wf;
        half8 f2 = *(const half8*)(tb +  8192 + frow + fslot) * wf;
        half8 f3 = *(const half8*)(tb + 12288 + frow + fslot) * wf;
#pragma unroll
        for (int j = 0; j < 8; ++j) {
            const float dj = (float)df[j];
            macc0 = fmaf((float)f0[j], dj, macc0);
            macc1 = fmaf((float)f1[j], dj, macc1);
            macc2 = fmaf((float)f2[j], dj, macc2);
            macc3 = fmaf((float)f3[j], dj, macc3);
        }
        a00 = __builtin_amdgcn_mfma_f32_32x32x16_f16(f0, f0, a00, 0, 0, 0);
        a01 = __builtin_amdgcn_mfma_f32_32x32x16_f16(f0, f1, a01, 0, 0, 0);
        a02 = __builtin_amdgcn_mfma_f32_32x32x16_f16(f0, f2, a02, 0, 0, 0);
        a03 = __builtin_amdgcn_mfma_f32_32x32x16_f16(f0, f3, a03, 0, 0, 0);
        a11 = __builtin_amdgcn_mfma_f32_32x32x16_f16(f1, f1, a11, 0, 0, 0);
        a12 = __builtin_amdgcn_mfma_f32_32x32x16_f16(f1, f2, a12, 0, 0, 0);
        a13 = __builtin_amdgcn_mfma_f32_32x32x16_f16(f1, f3, a13, 0, 0, 0);
        a22 = __builtin_amdgcn_mfma_f32_32x32x16_f16(f2, f2, a22, 0, 0, 0);
        a23 = __builtin_amdgcn_mfma_f32_32x32x16_f16(f2, f3, a23, 0, 0, 0);
        a33 = __builtin_amdgcn_mfma_f32_32x32x16_f16(f3, f3, a33, 0, 0, 0);
        __syncthreads();
    }

    {
        float* M = (float*)(smem + 32768);
        const int base = (w * 2 + (l >> 5)) * 128 + (l & 31);
        M[base +  0] = macc0;  M[base + 32] = macc1;
        M[base + 64] = macc2;  M[base + 96] = macc3;
    }
    _Float16* Gp = (_Float16*)(ws + GP_OFF) + (size_t)(b * NCHUNK + chunk) * 10240;
    float* Mp = (float*)(ws + MP_OFF) + (size_t)(b * NCHUNK + chunk) * KK;
    float* R = (float*)smem;

#define PHASE(p_, A0_, A1_)                                                    \
    {                                                                          \
        *(f32x16*)(R + (w * 2 + 0) * 1024 + l * 16) = A0_;                     \
        *(f32x16*)(R + (w * 2 + 1) * 1024 + l * 16) = A1_;                     \
        __syncthreads();                                                       \
        _Pragma("unroll")                                                      \
        for (int pass = 0; pass < 2; ++pass) {                                 \
            const int e = pass * 1024 + tid * 4;                               \
            float4 s0 = *(float4*)(R + e);                                     \
            float4 s1 = *(float4*)(R + 2048 + e);                              \
            float4 s2 = *(float4*)(R + 4096 + e);                              \
            float4 s3 = *(float4*)(R + 6144 + e);                              \
            float sx = s0.x + s1.x + s2.x + s3.x;                              \
            float sy = s0.y + s1.y + s2.y + s3.y;                              \
            float sz = s0.z + s1.z + s2.z + s3.z;                              \
            float sw = s0.w + s1.w + s2.w + s3.w;                              \
            half4 h = { (_Float16)sx, (_Float16)sy, (_Float16)sz, (_Float16)sw }; \
            *(half4*)(Gp + (p_) * 2048 + e) = h;                               \
        }                                                                      \
        if ((p_) == 0 && tid < 128) {                                          \
            const float* M = (const float*)(smem + 32768);                     \
            float s = 0.f;                                                     \
            _Pragma("unroll")                                                  \
            for (int c8 = 0; c8 < 8; ++c8) s += M[c8 * 128 + tid];             \
            Mp[tid] = s;                                                       \
        }                                                                      \
        __syncthreads();                                                       \
    }

    PHASE(0, a00, a01)
    PHASE(1, a02, a03)
    PHASE(2, a11, a12)
    PHASE(3, a13, a22)
    PHASE(4, a23, a33)
#undef PHASE
#undef GLOAD
#undef DSWRITE
}

// ---------------------------------------------------------------------------
// K2: reduce partial tiles -> G f32 + sigma^2 I.  COALESCED: each thread owns
// one contiguous half8 granule, sums over chunks (layout-agnostic), then
// decodes C/D layout once and writes direct + mirror.
// grid = BATCH*5 blocks (2 tiles each) x 256 threads.
// ---------------------------------------------------------------------------
__global__ __launch_bounds__(256) void reduce_kernel(
    const float* __restrict__ sig, unsigned char* __restrict__ ws)
{
    const int tid = threadIdx.x;
    const int b  = blockIdx.x / 5;
    const int t2 = blockIdx.x % 5;

    const int e_local = tid * 8;                // 0..2047 within 2 tiles
    const int tile = t2 * 2 + (e_local >> 10);  // 0..9
    const int off  = e_local & 1023;
    const int lane = off >> 4;
    const int r0   = off & 15;                  // 0 or 8

    const _Float16* Gp = (const _Float16*)(ws + GP_OFF)
                       + (size_t)b * NCHUNK * 10240 + (size_t)t2 * 2048 + e_local;
    float s[8] = {0.f,0.f,0.f,0.f,0.f,0.f,0.f,0.f};
#pragma unroll
    for (int ch = 0; ch < NCHUNK; ++ch) {
        half8 v = *(const half8*)(Gp + (size_t)ch * 10240);
#pragma unroll
        for (int j = 0; j < 8; ++j) s[j] += (float)v[j];
    }

    static const int TT[10] = {0,0,0,0,1,1,1,2,2,3};
    static const int UU[10] = {0,1,2,3,1,2,3,2,3,3};
    const int tt = TT[tile], uu = UU[tile];
    const int C = uu * 32 + (lane & 31);
    float* G = (float*)(ws + G_OFF) + (size_t)b * 16384;
    const float sg = sig[0];
#pragma unroll
    for (int j = 0; j < 8; ++j) {
        const int reg = r0 + j;
        const int row = (reg & 3) + 8 * (reg >> 2) + 4 * (lane >> 5);
        const int Rr = tt * 32 + row;
        float v = s[j];
        G[Rr * KK + C] = (Rr == C) ? v + sg : v;
        if (tt != uu) G[C * KK + Rr] = v;
    }
}

// ---------------------------------------------------------------------------
// K3: per-batch m reduce + CG solve of G x = m.  8 blocks x 128 threads.
// ---------------------------------------------------------------------------
__device__ __forceinline__ float blockDot(float a, float bvl, float* red)
{
    float v = a * bvl;
#pragma unroll
    for (int off = 32; off > 0; off >>= 1) v += __shfl_down(v, off, 64);
    const int wid = threadIdx.x >> 6;
    if ((threadIdx.x & 63) == 0) red[wid] = v;
    __syncthreads();
    float s = red[0] + red[1];
    __syncthreads();
    return s;
}

__global__ __launch_bounds__(128, 1) void solve_kernel(
    const unsigned char* __restrict__ ws, float* __restrict__ out)
{
    const int b = blockIdx.x;
    const int i = threadIdx.x;

    __shared__ float ps[KK];
    __shared__ float red[2];

    const float* G  = (const float*)(ws + G_OFF) + (size_t)b * 16384;
    const float* Mp = (const float*)(ws + MP_OFF) + (size_t)b * NCHUNK * KK;

    float Gr[KK];
#pragma unroll
    for (int j = 0; j < KK; ++j) Gr[j] = G[j * KK + i];   // symmetric: col i == row i

    float mvv = 0.f;
#pragma unroll
    for (int ch = 0; ch < NCHUNK; ++ch) mvv += Mp[ch * KK + i];

    float x = 0.f, r = mvv, p = r;
    ps[i] = p;
    float rs = blockDot(r, r, red);

    for (int it = 0; it < NITER; ++it) {
        float q0 = 0.f, q1 = 0.f, q2 = 0.f, q3 = 0.f;
#pragma unroll
        for (int u = 0; u < 32; ++u) {
            float4 pv = *reinterpret_cast<const float4*>(&ps[4 * u]);
            q0 = fmaf(Gr[4 * u + 0], pv.x, q0);
            q1 = fmaf(Gr[4 * u + 1], pv.y, q1);
            q2 = fmaf(Gr[4 * u + 2], pv.z, q2);
            q3 = fmaf(Gr[4 * u + 3], pv.w, q3);
        }
        float q = (q0 + q1) + (q2 + q3);

        float pq    = blockDot(p, q, red);
        float alpha = rs / (pq + 1e-30f);
        x = fmaf(alpha, p, x);
        r = fmaf(-alpha, q, r);
        float rs2  = blockDot(r, r, red);
        float beta = rs2 / (rs + 1e-30f);
        rs = rs2;
        p  = fmaf(beta, p, r);
        ps[i] = p;
        __syncthreads();
    }
    out[(size_t)b * KK + i] = x;
}

// ---------------------------------------------------------------------------
extern "C" void kernel_launch(void* const* d_in, const int* in_sizes, int n_in,
                              void* d_out, int out_size, void* d_ws, size_t ws_size,
                              hipStream_t stream)
{
    const float* data = (const float*)d_in[0];
    const float* mask = (const float*)d_in[1];
    const float* mult = (const float*)d_in[2];
    const float* sig  = (const float*)d_in[3];
    unsigned char* ws = (unsigned char*)d_ws;
    float* out = (float*)d_out;

    prep_kernel  <<<256, 256, 0, stream>>>(data, mask, mult, ws);
    gram_kernel  <<<BATCH * NCHUNK, 256, 0, stream>>>(ws);
    reduce_kernel<<<BATCH * 5, 256, 0, stream>>>(sig, ws);
    solve_kernel <<<BATCH, 128, 0, stream>>>(ws, out);
}